// Round 6
// baseline (81.165 us; speedup 1.0000x reference)
//
#include <hip/hip_runtime.h>

constexpr int NTOK = 262144;
constexpr int D    = 64;   // CODE_DIM
constexpr int K    = 16;   // NUM_CODES
constexpr int TPB  = 256;
constexpr int ROW4 = D / 4;          // 16 float4 per token row
constexpr int H4   = ROW4 / 2;       // 8 float4 per half-row

__global__ __launch_bounds__(TPB) void quantizer_kernel(
    const float* __restrict__ x, const float* __restrict__ cb, float* __restrict__ out)
{
    const int tid  = threadIdx.x;
    const int lane = tid & 63;
    const int gid  = blockIdx.x * TPB + tid;
    const int t    = gid >> 1;               // token
    const int h    = gid & 1;                // which half of the row

    const float4* __restrict__ X4  = reinterpret_cast<const float4*>(x);
    const float4* __restrict__ CB4 = reinterpret_cast<const float4*>(cb);
    float4* __restrict__ out4      = reinterpret_cast<float4*>(out);

    // ---- Pass A: own half-row (8 float4, 128B lane stride) ----
    float4 xr[H4];
#pragma unroll
    for (int q = 0; q < H4; ++q) xr[q] = X4[(size_t)t * ROW4 + h * H4 + q];

    // ---- distances: two f32 16-term blocks (bit-identical inner math to R5),
    //      f64 combine within thread, f64 pair-combine via shfl_xor(1).
    //      (p0+p1)+(p2+p3) reassociation: safe vs f32-reference gaps. ----
    double best = 1e300;
    int bidx = 0;
#pragma unroll
    for (int k = 0; k < K; ++k) {
        double a = 0.0;
#pragma unroll
        for (int b = 0; b < 2; ++b) {
            float p = 0.f;
#pragma unroll
            for (int j = 0; j < 4; ++j) {
                float4 c  = CB4[k * ROW4 + h * H4 + b * 4 + j];  // wave-uniform per (k,b,j,h-parity)? h varies by lane parity -> vector load, 4KiB L1-resident
                float4 xv = xr[b * 4 + j];
                float d0 = xv.x - c.x, d1 = xv.y - c.y;
                float d2 = xv.z - c.z, d3 = xv.w - c.w;
                p = fmaf(d0, d0, p);
                p = fmaf(d1, d1, p);
                p = fmaf(d2, d2, p);
                p = fmaf(d3, d3, p);
            }
            a += (double)p;
        }
        a += __shfl_xor(a, 1);               // pair-combine: both lanes get identical f64 total
        if (a < best) { best = a; bidx = k; }
    }

    // ---- Residual: wave spans 32 tokens -> 512 float4 region, 8 coalesced iters.
    //      float4 i=j*64+lane -> token-in-wave i>>4 = j*4+(lane>>4), quarter i&15 = lane&15.
    //      bidx owner pair starts at lane 2*(i>>4). x re-load coalesced, L2-hot. ----
    const int wtok      = (blockIdx.x * TPB + (tid & ~63)) >> 1;   // wave's first token
    const size_t xbase  = (size_t)wtok * ROW4;
    const size_t rbase  = (size_t)NTOK * (K / 4) + xbase;
    const int q = lane & 15;
#pragma unroll
    for (int j = 0; j < 8; ++j) {
        const int srclane = ((j * 4 + (lane >> 4)) << 1);
        const int b  = __shfl(bidx, srclane);
        float4 xv = X4[xbase + j * 64 + lane];
        float4 c  = CB4[b * ROW4 + q];
        float4 r;
        r.x = xv.x - c.x; r.y = xv.y - c.y;
        r.z = xv.z - c.z; r.w = xv.w - c.w;
        out4[rbase + j * 64 + lane] = r;
    }

    // ---- Onehot: wave spans 32 tokens -> 128 float4, 2 coalesced iters.
    //      float4 i=j*64+lane -> token i>>2 = j*16+(lane>>2), sub i&3 = lane&3. ----
    const size_t ohbase = (size_t)wtok * (K / 4);
    const int sub = lane & 3;
#pragma unroll
    for (int j = 0; j < 2; ++j) {
        const int srclane = ((j * 16 + (lane >> 2)) << 1);
        const int b = __shfl(bidx, srclane);
        float4 v;
        v.x = (b == sub * 4 + 0) ? 1.f : 0.f;
        v.y = (b == sub * 4 + 1) ? 1.f : 0.f;
        v.z = (b == sub * 4 + 2) ? 1.f : 0.f;
        v.w = (b == sub * 4 + 3) ? 1.f : 0.f;
        out4[ohbase + j * 64 + lane] = v;
    }
}

extern "C" void kernel_launch(void* const* d_in, const int* in_sizes, int n_in,
                              void* d_out, int out_size, void* d_ws, size_t ws_size,
                              hipStream_t stream) {
    const float* x  = (const float*)d_in[0];   // [262144, 64] fp32
    const float* cb = (const float*)d_in[1];   // [16, 64] fp32
    float* out = (float*)d_out;                // [N*16 onehot | N*64 residual] fp32

    const int blocks = (NTOK * 2) / TPB;       // 2048 blocks, 8192 waves
    quantizer_kernel<<<blocks, TPB, 0, stream>>>(x, cb, out);
}

// Round 7
// 74.839 us; speedup vs baseline: 1.0845x; 1.0845x over previous
//
#include <hip/hip_runtime.h>

constexpr int NTOK  = 262144;
constexpr int D     = 64;    // CODE_DIM
constexpr int K     = 16;    // NUM_CODES
constexpr int TPB   = 256;
constexpr int ROW4  = D / 4;                 // 16 float4 per token row
constexpr int WTOK  = 64;                    // tokens per wave-tile (1/lane)
constexpr int NTILE = NTOK / WTOK;           // 4096
constexpr int NBLK  = 512;
constexpr int NWAVE = NBLK * (TPB / 64);     // 2048 waves -> 2 tiles/wave

__device__ __forceinline__ int argmin16(const float4* __restrict__ CB4,
                                        const float4 (&xr)[ROW4])
{
    // BIT-IDENTICAL to R2/R3/R5 (proven absmax==0): f32 16-term blocks,
    // f64 sequential accumulate, strict-< first-occurrence argmin.
    double best = 1e300;
    int bidx = 0;
#pragma unroll
    for (int k = 0; k < K; ++k) {
        double a = 0.0;
#pragma unroll
        for (int b = 0; b < 4; ++b) {
            float p = 0.f;
#pragma unroll
            for (int j = 0; j < 4; ++j) {
                float4 c  = CB4[k * ROW4 + b * 4 + j];   // wave-uniform -> scalar K$
                float4 xv = xr[b * 4 + j];
                float d0 = xv.x - c.x, d1 = xv.y - c.y;
                float d2 = xv.z - c.z, d3 = xv.w - c.w;
                p = fmaf(d0, d0, p);
                p = fmaf(d1, d1, p);
                p = fmaf(d2, d2, p);
                p = fmaf(d3, d3, p);
            }
            a += (double)p;
        }
        if (a < best) { best = a; bidx = k; }
    }
    return bidx;
}

__device__ __forceinline__ void flush_tile(float4* __restrict__ out4,
                                           const float4* __restrict__ CB4,
                                           float4* __restrict__ slab,
                                           const float4 (&xr)[ROW4],
                                           int bidx, int tile, int lane)
{
    // residual from registers -> wave-private LDS (XOR swizzle, conflict-free;
    // same-wave produce/consume: lgkmcnt only, NO barrier)
#pragma unroll
    for (int q = 0; q < ROW4; ++q) {
        float4 c  = CB4[bidx * ROW4 + q];    // per-lane idx, 4 KiB L1-resident
        float4 xv = xr[q];
        float4 r;
        r.x = xv.x - c.x; r.y = xv.y - c.y;
        r.z = xv.z - c.z; r.w = xv.w - c.w;
        slab[lane * ROW4 + (q ^ (lane & 15))] = r;
    }
    // coalesced residual store: 1 KiB per instruction
    const size_t rbase = (size_t)NTOK * (K / 4) + (size_t)tile * WTOK * ROW4;
#pragma unroll
    for (int it = 0; it < ROW4; ++it) {
        int i = it * 64 + lane, tok = i >> 4, q = i & 15;
        out4[rbase + i] = slab[tok * ROW4 + (q ^ (tok & 15))];
    }
    // onehot via shfl (token-in-wave == owner lane), coalesced
    const size_t ohbase = (size_t)tile * WTOK * (K / 4);
    const int sub = lane & 3;
#pragma unroll
    for (int j = 0; j < 4; ++j) {
        int i = j * 64 + lane;
        int token = i >> 2;                  // = j*16 + (lane>>2)
        int b = __shfl(bidx, token);
        float4 v;
        v.x = (b == sub * 4 + 0) ? 1.f : 0.f;
        v.y = (b == sub * 4 + 1) ? 1.f : 0.f;
        v.z = (b == sub * 4 + 2) ? 1.f : 0.f;
        v.w = (b == sub * 4 + 3) ? 1.f : 0.f;
        out4[ohbase + i] = v;
    }
}

__global__ __launch_bounds__(TPB, 2) void quantizer_kernel(
    const float* __restrict__ x, const float* __restrict__ cb, float* __restrict__ out)
{
    __shared__ float4 slab_all[TPB / 64][WTOK * ROW4];   // 4 x 16 KiB, wave-private
    const int tid  = threadIdx.x;
    const int lane = tid & 63;
    const int wv   = tid >> 6;
    float4* slab   = slab_all[wv];

    const int gw = blockIdx.x * (TPB / 64) + wv;         // global wave id [0,2048)
    const int t0 = gw, t1 = gw + NWAVE;                  // this wave's two tiles

    const float4* __restrict__ X4  = reinterpret_cast<const float4*>(x);
    const float4* __restrict__ CB4 = reinterpret_cast<const float4*>(cb);
    float4* __restrict__ out4      = reinterpret_cast<float4*>(out);

    float4 xrA[ROW4], xrB[ROW4];

    // tile A: load + argmin
    const size_t baseA = (size_t)(t0 * WTOK + lane) * ROW4;
#pragma unroll
    for (int q = 0; q < ROW4; ++q) xrA[q] = X4[baseA + q];
    int bA = argmin16(CB4, xrA);

    // issue tile B loads BEFORE tile A's store phase -> reads overlap writes
    const size_t baseB = (size_t)(t1 * WTOK + lane) * ROW4;
#pragma unroll
    for (int q = 0; q < ROW4; ++q) xrB[q] = X4[baseB + q];

    flush_tile(out4, CB4, slab, xrA, bA, t0, lane);      // stores (HBM W) || xrB loads (HBM R)

    int bB = argmin16(CB4, xrB);
    flush_tile(out4, CB4, slab, xrB, bB, t1, lane);
}

extern "C" void kernel_launch(void* const* d_in, const int* in_sizes, int n_in,
                              void* d_out, int out_size, void* d_ws, size_t ws_size,
                              hipStream_t stream) {
    const float* x  = (const float*)d_in[0];   // [262144, 64] fp32
    const float* cb = (const float*)d_in[1];   // [16, 64] fp32
    float* out = (float*)d_out;                // [N*16 onehot | N*64 residual] fp32

    quantizer_kernel<<<NBLK, TPB, 0, stream>>>(x, cb, out);
}

// Round 8
// 32.880 us; speedup vs baseline: 2.4685x; 2.2761x over previous
//
#include <hip/hip_runtime.h>

constexpr int NTOK = 262144;
constexpr int D    = 64;   // CODE_DIM
constexpr int K    = 16;   // NUM_CODES
constexpr int TPB  = 256;
constexpr int ROW4 = D / 4;          // 16 float4 per token row
constexpr int TOKB = 64;             // tokens per block (4 threads/token)

__global__ __launch_bounds__(TPB, 8) void quantizer_kernel(
    const float* __restrict__ x, const float* __restrict__ cb, float* __restrict__ out)
{
    __shared__ float4 P[4][4][TOKB];   // [quarter][code-quad][token] = 16 KiB

    const int tid = threadIdx.x;
    const int ln  = tid & 63;                                   // token within block
    const int w   = __builtin_amdgcn_readfirstlane(tid >> 6);   // wave id = quarter (SGPR!)

    const float4* __restrict__ X4  = reinterpret_cast<const float4*>(x);
    const float4* __restrict__ CB4 = reinterpret_cast<const float4*>(cb);
    float4* __restrict__ out4      = reinterpret_cast<float4*>(out);

    const size_t blk4 = (size_t)blockIdx.x * TOKB * ROW4;   // block x region (1024 float4)

    // ---- coalesced preload of store-phase x (1 KiB/wave/instr); latency hidden under dist ----
    float4 xs[4];
#pragma unroll
    for (int it = 0; it < 4; ++it) xs[it] = X4[blk4 + it * TPB + tid];

    // ---- own quarter of own token (256B lane stride; block consumes every line) ----
    float4 xr[4];
#pragma unroll
    for (int j = 0; j < 4; ++j) xr[j] = X4[blk4 + (size_t)ln * ROW4 + w * 4 + j];

    // ---- 16 partials: f32 fmaf chain per 16-elem quarter — BIT-IDENTICAL to the proven
    //      R5 inner block (quarter w == b-block w). Write each quad to LDS immediately. ----
#pragma unroll
    for (int q = 0; q < 4; ++q) {
        float pq[4];
#pragma unroll
        for (int c = 0; c < 4; ++c) {
            const int k = 4 * q + c;
            float pp = 0.f;
#pragma unroll
            for (int j = 0; j < 4; ++j) {
                float4 cc = CB4[k * ROW4 + w * 4 + j];   // SGPR-uniform -> s_load, K$-hot
                float4 xv = xr[j];
                float d0 = xv.x - cc.x, d1 = xv.y - cc.y;
                float d2 = xv.z - cc.z, d3 = xv.w - cc.w;
                pp = fmaf(d0, d0, pp);
                pp = fmaf(d1, d1, pp);
                pp = fmaf(d2, d2, pp);
                pp = fmaf(d3, d3, pp);
            }
            pq[c] = pp;
        }
        P[w][q][ln] = make_float4(pq[0], pq[1], pq[2], pq[3]);
    }
    __syncthreads();   // the ONLY barrier

    // ---- combine partials in f64, quarter order 0,1,2,3 == proven b-order;
    //      strict-< first-occurrence argmin, k ascending. All 4 waves redundantly
    //      compute the same bidx for token==ln (deterministic). ----
    double best = 1e300;
    int bidx = 0;
#pragma unroll
    for (int q = 0; q < 4; ++q) {
        float4 f0 = P[0][q][ln], f1 = P[1][q][ln], f2 = P[2][q][ln], f3 = P[3][q][ln];
#define COMB(CMP, KK)                                                  \
        { double a = (double)f0.CMP; a += f1.CMP; a += f2.CMP; a += f3.CMP; \
          if (a < best) { best = a; bidx = 4 * q + KK; } }
        COMB(x, 0) COMB(y, 1) COMB(z, 2) COMB(w, 3)
#undef COMB
    }

    // ---- onehot: one coalesced float4 per thread (block region = 4 KiB) ----
    {
        const int tok = tid >> 2;                 // token in block [0,64)
        const int b   = __shfl(bidx, tok);        // bidx[lane==tok], identical in every wave
        const int sub = tid & 3;
        float4 v;
        v.x = (b == sub * 4 + 0) ? 1.f : 0.f;
        v.y = (b == sub * 4 + 1) ? 1.f : 0.f;
        v.z = (b == sub * 4 + 2) ? 1.f : 0.f;
        v.w = (b == sub * 4 + 3) ? 1.f : 0.f;
        out4[(size_t)blockIdx.x * (TOKB * K / 4) + tid] = v;
    }

    // ---- residual: from preloaded xs, coalesced stores (block region = 16 KiB) ----
    const size_t rbase = (size_t)NTOK * (K / 4) + blk4;
#pragma unroll
    for (int it = 0; it < 4; ++it) {
        const int i   = it * TPB + tid;           // float4 index in block region
        const int tok = i >> 4;                   // [0,64)
        const int b   = __shfl(bidx, tok);
        float4 c  = CB4[b * ROW4 + (tid & 15)];   // per-lane b, 4 KiB L1-resident
        float4 xv = xs[it];
        float4 r;
        r.x = xv.x - c.x; r.y = xv.y - c.y;
        r.z = xv.z - c.z; r.w = xv.w - c.w;
        out4[rbase + i] = r;
    }
}

extern "C" void kernel_launch(void* const* d_in, const int* in_sizes, int n_in,
                              void* d_out, int out_size, void* d_ws, size_t ws_size,
                              hipStream_t stream) {
    const float* x  = (const float*)d_in[0];   // [262144, 64] fp32
    const float* cb = (const float*)d_in[1];   // [16, 64] fp32
    float* out = (float*)d_out;                // [N*16 onehot | N*64 residual] fp32

    quantizer_kernel<<<NTOK / TOKB, TPB, 0, stream>>>(x, cb, out);
}

// Round 9
// 28.888 us; speedup vs baseline: 2.8097x; 1.1382x over previous
//
#include <hip/hip_runtime.h>

constexpr int NTOK = 262144;
constexpr int D    = 64;   // CODE_DIM
constexpr int K    = 16;   // NUM_CODES
constexpr int TPB  = 256;
constexpr int ROW4 = D / 4;          // 16 float4 per token row
constexpr int TOKB = 64;             // tokens per block (4 threads/token)

__global__ __launch_bounds__(TPB, 8) void quantizer_kernel(
    const float* __restrict__ x, const float* __restrict__ cb, float* __restrict__ out)
{
    // 16 KiB slab, reused: x-transpose, then distance partials.
    // Logical [token][col4] at phys token*16 + (col ^ (token&15))  (float4 units).
    __shared__ float4 slab[TOKB * ROW4];

    const int tid = threadIdx.x;
    const int ln  = tid & 63;                                   // token within block
    const int w   = __builtin_amdgcn_readfirstlane(tid >> 6);   // wave id = quarter (SGPR)

    const float4* __restrict__ X4  = reinterpret_cast<const float4*>(x);
    const float4* __restrict__ CB4 = reinterpret_cast<const float4*>(cb);
    float4* __restrict__ out4      = reinterpret_cast<float4*>(out);

    const size_t blk4 = (size_t)blockIdx.x * TOKB * ROW4;

    // ---- Phase 0: the ONLY global read of x — fully coalesced (1 KiB/wave/instr).
    //      Keep in regs for the residual phase; also stage into swizzled slab. ----
    float4 xs[4];
#pragma unroll
    for (int it = 0; it < 4; ++it) {
        const int i = it * TPB + tid;
        xs[it] = X4[blk4 + i];
        const int t = i >> 4, c = i & 15;
        slab[(t << 4) + (c ^ (t & 15))] = xs[it];   // conflict-free (8/bank-group)
    }
    __syncthreads();   // barrier 1

    // ---- Phase 1: own token's quarter from LDS (wave w touches ONLY cols w*4..w*4+3) ----
    float4 xr[4];
#pragma unroll
    for (int j = 0; j < 4; ++j)
        xr[j] = slab[(ln << 4) + ((w * 4 + j) ^ (ln & 15))];

    // ---- Phase 2: 16 partials — f32 fmaf chain per 16-elem quarter, BIT-IDENTICAL
    //      to proven R5/R8 inner block. Write back into the SAME slots this wave
    //      just consumed (per-wave disjoint -> no barrier needed here). ----
#pragma unroll
    for (int q = 0; q < 4; ++q) {
        float pq[4];
#pragma unroll
        for (int c = 0; c < 4; ++c) {
            const int k = 4 * q + c;
            float pp = 0.f;
#pragma unroll
            for (int j = 0; j < 4; ++j) {
                float4 cc = CB4[k * ROW4 + w * 4 + j];   // SGPR-uniform -> s_load, K$-hot
                float4 xv = xr[j];
                float d0 = xv.x - cc.x, d1 = xv.y - cc.y;
                float d2 = xv.z - cc.z, d3 = xv.w - cc.w;
                pp = fmaf(d0, d0, pp);
                pp = fmaf(d1, d1, pp);
                pp = fmaf(d2, d2, pp);
                pp = fmaf(d3, d3, pp);
            }
            pq[c] = pp;
        }
        slab[(ln << 4) + ((w * 4 + q) ^ (ln & 15))] =
            make_float4(pq[0], pq[1], pq[2], pq[3]);
    }
    __syncthreads();   // barrier 2

    // ---- Phase 3: combine in f64, quarter order 0,1,2,3 == proven b-order;
    //      strict-< first-occurrence argmin, k ascending. Code k=4q+cc partial of
    //      quarter w' lives at slab[ln][w'*4+q].comp[cc]. ----
    double best = 1e300;
    int bidx = 0;
#pragma unroll
    for (int q = 0; q < 4; ++q) {
        float4 f0 = slab[(ln << 4) + ((0 * 4 + q) ^ (ln & 15))];
        float4 f1 = slab[(ln << 4) + ((1 * 4 + q) ^ (ln & 15))];
        float4 f2 = slab[(ln << 4) + ((2 * 4 + q) ^ (ln & 15))];
        float4 f3 = slab[(ln << 4) + ((3 * 4 + q) ^ (ln & 15))];
#define COMB(CMP, KK)                                                       \
        { double a = (double)f0.CMP; a += f1.CMP; a += f2.CMP; a += f3.CMP; \
          if (a < best) { best = a; bidx = 4 * q + KK; } }
        COMB(x, 0) COMB(y, 1) COMB(z, 2) COMB(w, 3)
#undef COMB
    }

    // ---- onehot: one coalesced float4 per thread (block region = 4 KiB) ----
    {
        const int tok = tid >> 2;                 // token in block [0,64)
        const int b   = __shfl(bidx, tok);        // identical across waves
        const int sub = tid & 3;
        float4 v;
        v.x = (b == sub * 4 + 0) ? 1.f : 0.f;
        v.y = (b == sub * 4 + 1) ? 1.f : 0.f;
        v.z = (b == sub * 4 + 2) ? 1.f : 0.f;
        v.w = (b == sub * 4 + 3) ? 1.f : 0.f;
        out4[(size_t)blockIdx.x * (TOKB * K / 4) + tid] = v;
    }

    // ---- residual: from xs regs, coalesced stores (block region = 16 KiB) ----
    const size_t rbase = (size_t)NTOK * (K / 4) + blk4;
#pragma unroll
    for (int it = 0; it < 4; ++it) {
        const int i   = it * TPB + tid;
        const int tok = i >> 4;
        const int b   = __shfl(bidx, tok);
        float4 c  = CB4[b * ROW4 + (tid & 15)];   // per-lane b, 4 KiB L1-resident
        float4 xv = xs[it];
        float4 r;
        r.x = xv.x - c.x; r.y = xv.y - c.y;
        r.z = xv.z - c.z; r.w = xv.w - c.w;
        out4[rbase + i] = r;
    }
}

extern "C" void kernel_launch(void* const* d_in, const int* in_sizes, int n_in,
                              void* d_out, int out_size, void* d_ws, size_t ws_size,
                              hipStream_t stream) {
    const float* x  = (const float*)d_in[0];   // [262144, 64] fp32
    const float* cb = (const float*)d_in[1];   // [16, 64] fp32
    float* out = (float*)d_out;                // [N*16 onehot | N*64 residual] fp32

    quantizer_kernel<<<NTOK / TOKB, TPB, 0, stream>>>(x, cb, out);
}